// Round 1
// baseline (542.588 us; speedup 1.0000x reference)
//
#include <hip/hip_runtime.h>
#include <hip/hip_bf16.h>
#include <math.h>

// Problem constants
#define BB 32
#define LL 4100
#define SS 1024
#define EE 16
#define HH 4
#define DHD 4
#define NCC 10

// Workspace layout (in floats)
#define OFF_PE   0                       // S*E = 16384
#define OFF_H1   16384                   // B*8*S = 262144
#define OFF_H2   (OFF_H1 + 262144)       // B*32*S = 1048576
#define OFF_XSRC (OFF_H2 + 1048576)      // B*S*E = 524288
#define OFF_Q    (OFF_XSRC + 524288)     // B*H*S*DH = 524288
#define OFF_K    (OFF_Q + 524288)
#define OFF_V    (OFF_K + 524288)
#define OFF_AO   (OFF_V + 524288)        // attention out [B,S,E]
#define OFF_Z    (OFF_AO + 524288)       // layer-1 output
#define OFF_Z2   OFF_XSRC                // reuse xsrc for final z2 (xsrc dead after post1)

__global__ __launch_bounds__(256) void pe_kernel(float* pe) {
    int idx = blockIdx.x * 256 + threadIdx.x;       // S*E = 16384
    int s = idx >> 4, e = idx & 15;
    int j = e >> 1;
    float div = powf(10000.f, -(float)j / 8.f);
    float ang = (float)s * div * (16.f / 1024.f);
    pe[idx] = (e & 1) ? cosf(ang) : sinf(ang);
}

__global__ __launch_bounds__(256) void conv1_kernel(const float* __restrict__ x,
        const float* __restrict__ w, const float* __restrict__ bias,
        const float* __restrict__ g, const float* __restrict__ bb,
        float* __restrict__ h1) {
    int idx = blockIdx.x * 256 + threadIdx.x;       // B*8*S
    int s = idx & 1023; int c = (idx >> 10) & 7; int b = idx >> 13;
    const float* xp = x + b * LL + 4 * s;
    float acc = bias[c];
    #pragma unroll
    for (int k = 0; k < 8; k++) acc += xp[k] * w[c * 8 + k];
    float inv = rsqrtf(1.f + 1e-5f);
    float v = acc * inv * g[c] + bb[c];
    h1[idx] = fmaxf(v, 0.f);
}

__global__ __launch_bounds__(256) void conv2_kernel(const float* __restrict__ h1,
        const float* __restrict__ w, const float* __restrict__ bias,
        const float* __restrict__ g, const float* __restrict__ bb,
        float* __restrict__ h2) {
    int s = blockIdx.x * 256 + threadIdx.x;
    int o = blockIdx.y, b = blockIdx.z;
    const float* hp = h1 + b * 8 * SS;
    float acc = bias[o];
    #pragma unroll
    for (int i = 0; i < 8; i++) {
        const float* row = hp + i * SS;
        const float* wr = w + (o * 8 + i) * 8;
        #pragma unroll
        for (int k = 0; k < 8; k++) {
            int t = s - 3 + k;
            if (t >= 0 && t < SS) acc += row[t] * wr[k];
        }
    }
    float inv = rsqrtf(1.f + 1e-5f);
    float v = acc * inv * g[o] + bb[o];
    h2[(b * 32 + o) * SS + s] = fmaxf(v, 0.f);
}

__global__ __launch_bounds__(256) void conv3_kernel(const float* __restrict__ h2,
        const float* __restrict__ dw, const float* __restrict__ pw,
        const float* __restrict__ g, const float* __restrict__ bb,
        float* __restrict__ xsrc) {
    __shared__ float sdw[1024], spw[256];
    int tid = threadIdx.x;
    for (int i = tid; i < 1024; i += 256) sdw[i] = dw[i];
    spw[tid] = pw[tid];
    __syncthreads();
    int s = blockIdx.x * 256 + tid; int b = blockIdx.y;
    const float* hb = h2 + b * 32 * SS;
    float gout[16];
    #pragma unroll 4
    for (int o = 0; o < 16; o++) {
        float acc = 0.f;
        #pragma unroll
        for (int c = 0; c < 2; c++) {
            const float* row = hb + (2 * o + c) * SS;
            const float* wr = sdw + (o * 2 + c) * 32;
            #pragma unroll
            for (int k = 0; k < 32; k++) {
                int t = s - 15 + k;
                if (t >= 0 && t < SS) acc += row[t] * wr[k];
            }
        }
        gout[o] = acc;
    }
    float inv = rsqrtf(1.f + 1e-5f);
    float* xp = xsrc + (b * SS + s) * 16;
    #pragma unroll
    for (int p = 0; p < 16; p++) {
        float acc = 0.f;
        #pragma unroll
        for (int o = 0; o < 16; o++) acc += spw[p * 16 + o] * gout[o];
        float v = acc * inv * g[p] + bb[p];
        xp[p] = fmaxf(v, 0.f);
    }
}

// QKV projection: t = xin[b,s,:] + pe[s,:];  {q,k,v}[e] = sum_f W[e,f]*t[f]
// Output layout: [B,H,S,DH] for contiguous float4 reads in attention.
__global__ __launch_bounds__(256) void qkv_kernel(const float* __restrict__ xin,
        const float* __restrict__ pe,
        const float* __restrict__ wq, const float* __restrict__ wk,
        const float* __restrict__ wv,
        float* __restrict__ q, float* __restrict__ k, float* __restrict__ v) {
    __shared__ float swq[256], swk[256], swv[256];
    int tid = threadIdx.x;
    swq[tid] = wq[tid]; swk[tid] = wk[tid]; swv[tid] = wv[tid];
    __syncthreads();
    int idx = blockIdx.x * 256 + tid;               // b*S + s
    int s = idx & 1023; int b = idx >> 10;
    float t[16];
    const float4* xp4 = (const float4*)(xin + (size_t)idx * 16);
    const float4* pp4 = (const float4*)(pe + s * 16);
    #pragma unroll
    for (int i = 0; i < 4; i++) {
        float4 a = xp4[i], p = pp4[i];
        t[4*i+0] = a.x + p.x; t[4*i+1] = a.y + p.y;
        t[4*i+2] = a.z + p.z; t[4*i+3] = a.w + p.w;
    }
    #pragma unroll
    for (int e = 0; e < 16; e++) {
        float aq = 0.f, ak = 0.f, av = 0.f;
        #pragma unroll
        for (int f = 0; f < 16; f++) {
            aq += swq[e * 16 + f] * t[f];
            ak += swk[e * 16 + f] * t[f];
            av += swv[e * 16 + f] * t[f];
        }
        int h = e >> 2, d = e & 3;
        size_t o = ((size_t)(b * HH + h) * SS + s) * DHD + d;
        q[o] = aq; k[o] = ak; v[o] = av;
    }
}

// Attention core: one block per (b*H+h, s-chunk of 256). K,V LDS-resident.
__global__ __launch_bounds__(256) void attn_kernel(const float* __restrict__ q,
        const float* __restrict__ k, const float* __restrict__ v,
        float* __restrict__ ao) {
    __shared__ float4 Ks[SS], Vs[SS];
    int bh = blockIdx.x;                             // b*H + h
    int tid = threadIdx.x;
    const float4* kp = (const float4*)(k + (size_t)bh * SS * DHD);
    const float4* vp = (const float4*)(v + (size_t)bh * SS * DHD);
    for (int t = tid; t < SS; t += 256) { Ks[t] = kp[t]; Vs[t] = vp[t]; }
    __syncthreads();
    int s = blockIdx.y * 256 + tid;
    float4 qv = ((const float4*)(q + (size_t)bh * SS * DHD))[s];
    const float wscale = 0.25f / 1024.f;             // scale * 1/n
    // pass 1: row max
    float m = -1e30f;
    for (int t = 0; t < SS; t++) {
        float4 kk = Ks[t];
        float d = qv.x*kk.x + qv.y*kk.y + qv.z*kk.z + qv.w*kk.w;
        float sc = d * wscale * fabsf((float)(t - s));
        m = fmaxf(m, sc);
    }
    // pass 2: exp-sum + weighted V accumulation
    float l = 0.f; float ox = 0.f, oy = 0.f, oz = 0.f, ow = 0.f;
    for (int t = 0; t < SS; t++) {
        float4 kk = Ks[t];
        float d = qv.x*kk.x + qv.y*kk.y + qv.z*kk.z + qv.w*kk.w;
        float sc = d * wscale * fabsf((float)(t - s));
        float p = __expf(sc - m);
        float4 vv = Vs[t];
        l += p; ox += p*vv.x; oy += p*vv.y; oz += p*vv.z; ow += p*vv.w;
    }
    float rl = 1.f / l;
    int b = bh >> 2, h = bh & 3;
    float* op = ao + ((size_t)(b * SS + s)) * 16 + h * 4;
    op[0] = ox * rl; op[1] = oy * rl; op[2] = oz * rl; op[3] = ow * rl;
}

// Fused epilogue: y = LN(ao, lna);  z = LN(y + res, ln)   (res may be null)
__global__ __launch_bounds__(256) void post_kernel(const float* __restrict__ ao,
        const float* __restrict__ res,
        const float* __restrict__ lna_g, const float* __restrict__ lna_b,
        const float* __restrict__ ln_g, const float* __restrict__ ln_b,
        float* __restrict__ z) {
    int idx = blockIdx.x * 256 + threadIdx.x;        // b*S+s
    float t[16];
    const float4* ap = (const float4*)(ao + (size_t)idx * 16);
    #pragma unroll
    for (int i = 0; i < 4; i++) {
        float4 a = ap[i];
        t[4*i+0] = a.x; t[4*i+1] = a.y; t[4*i+2] = a.z; t[4*i+3] = a.w;
    }
    float mu = 0.f;
    #pragma unroll
    for (int e = 0; e < 16; e++) mu += t[e];
    mu *= (1.f / 16.f);
    float var = 0.f;
    #pragma unroll
    for (int e = 0; e < 16; e++) { float d = t[e] - mu; var += d * d; }
    var *= (1.f / 16.f);
    float r = rsqrtf(var + 1e-5f);
    if (res) {
        const float4* rp = (const float4*)(res + (size_t)idx * 16);
        #pragma unroll
        for (int i = 0; i < 4; i++) {
            float4 a = rp[i];
            t[4*i+0] = (t[4*i+0]-mu)*r*lna_g[4*i+0] + lna_b[4*i+0] + a.x;
            t[4*i+1] = (t[4*i+1]-mu)*r*lna_g[4*i+1] + lna_b[4*i+1] + a.y;
            t[4*i+2] = (t[4*i+2]-mu)*r*lna_g[4*i+2] + lna_b[4*i+2] + a.z;
            t[4*i+3] = (t[4*i+3]-mu)*r*lna_g[4*i+3] + lna_b[4*i+3] + a.w;
        }
    } else {
        #pragma unroll
        for (int e = 0; e < 16; e++) t[e] = (t[e]-mu)*r*lna_g[e] + lna_b[e];
    }
    float mu2 = 0.f;
    #pragma unroll
    for (int e = 0; e < 16; e++) mu2 += t[e];
    mu2 *= (1.f / 16.f);
    float var2 = 0.f;
    #pragma unroll
    for (int e = 0; e < 16; e++) { float d = t[e] - mu2; var2 += d * d; }
    var2 *= (1.f / 16.f);
    float r2 = rsqrtf(var2 + 1e-5f);
    float4* zp = (float4*)(z + (size_t)idx * 16);
    #pragma unroll
    for (int i = 0; i < 4; i++) {
        float4 o;
        o.x = (t[4*i+0]-mu2)*r2*ln_g[4*i+0] + ln_b[4*i+0];
        o.y = (t[4*i+1]-mu2)*r2*ln_g[4*i+1] + ln_b[4*i+1];
        o.z = (t[4*i+2]-mu2)*r2*ln_g[4*i+2] + ln_b[4*i+2];
        o.w = (t[4*i+3]-mu2)*r2*ln_g[4*i+3] + ln_b[4*i+3];
        zp[i] = o;
    }
}

// Global-average-pool over S + final linear [16 -> 10]
__global__ __launch_bounds__(256) void pool_kernel(const float* __restrict__ z2,
        const float* __restrict__ ow, const float* __restrict__ ob,
        float* __restrict__ out) {
    __shared__ float red[256 * 16];
    int b = blockIdx.x, tid = threadIdx.x;
    float acc[16];
    #pragma unroll
    for (int e = 0; e < 16; e++) acc[e] = 0.f;
    for (int s = tid; s < SS; s += 256) {
        const float4* zp = (const float4*)(z2 + ((size_t)(b * SS + s)) * 16);
        #pragma unroll
        for (int i = 0; i < 4; i++) {
            float4 a = zp[i];
            acc[4*i+0] += a.x; acc[4*i+1] += a.y;
            acc[4*i+2] += a.z; acc[4*i+3] += a.w;
        }
    }
    #pragma unroll
    for (int e = 0; e < 16; e++) red[tid * 16 + e] = acc[e];
    __syncthreads();
    for (int off = 128; off > 0; off >>= 1) {
        if (tid < off) {
            #pragma unroll
            for (int e = 0; e < 16; e++) red[tid * 16 + e] += red[(tid + off) * 16 + e];
        }
        __syncthreads();
    }
    if (tid < NCC) {
        float a = ob[tid];
        #pragma unroll
        for (int e = 0; e < 16; e++) a += (red[e] * (1.f / 1024.f)) * ow[tid * 16 + e];
        out[b * NCC + tid] = a;
    }
}

extern "C" void kernel_launch(void* const* d_in, const int* in_sizes, int n_in,
                              void* d_out, int out_size, void* d_ws, size_t ws_size,
                              hipStream_t stream) {
    const float* x       = (const float*)d_in[0];
    const float* patch_w = (const float*)d_in[1];
    const float* patch_b = (const float*)d_in[2];
    const float* bn1_g   = (const float*)d_in[3];
    const float* bn1_b   = (const float*)d_in[4];
    const float* emb_w   = (const float*)d_in[5];
    const float* emb_b   = (const float*)d_in[6];
    const float* bn2_g   = (const float*)d_in[7];
    const float* bn2_b   = (const float*)d_in[8];
    const float* dw_w    = (const float*)d_in[9];
    const float* pw_w    = (const float*)d_in[10];
    const float* bn3_g   = (const float*)d_in[11];
    const float* bn3_b   = (const float*)d_in[12];
    const float* q1_w    = (const float*)d_in[13];
    const float* k1_w    = (const float*)d_in[14];
    const float* v1_w    = (const float*)d_in[15];
    const float* lna1_g  = (const float*)d_in[16];
    const float* lna1_b  = (const float*)d_in[17];
    const float* ln1_g   = (const float*)d_in[18];
    const float* ln1_b   = (const float*)d_in[19];
    const float* q2_w    = (const float*)d_in[20];
    const float* k2_w    = (const float*)d_in[21];
    const float* v2_w    = (const float*)d_in[22];
    const float* lna2_g  = (const float*)d_in[23];
    const float* lna2_b  = (const float*)d_in[24];
    const float* ln2_g   = (const float*)d_in[25];
    const float* ln2_b   = (const float*)d_in[26];
    const float* out_w   = (const float*)d_in[27];
    const float* out_b   = (const float*)d_in[28];

    float* ws   = (float*)d_ws;
    float* pe   = ws + OFF_PE;
    float* h1   = ws + OFF_H1;
    float* h2   = ws + OFF_H2;
    float* xsrc = ws + OFF_XSRC;
    float* q    = ws + OFF_Q;
    float* k    = ws + OFF_K;
    float* v    = ws + OFF_V;
    float* ao   = ws + OFF_AO;
    float* z    = ws + OFF_Z;
    float* z2   = ws + OFF_Z2;
    float* out  = (float*)d_out;

    pe_kernel<<<64, 256, 0, stream>>>(pe);
    conv1_kernel<<<1024, 256, 0, stream>>>(x, patch_w, patch_b, bn1_g, bn1_b, h1);
    conv2_kernel<<<dim3(4, 32, BB), 256, 0, stream>>>(h1, emb_w, emb_b, bn2_g, bn2_b, h2);
    conv3_kernel<<<dim3(4, BB), 256, 0, stream>>>(h2, dw_w, pw_w, bn3_g, bn3_b, xsrc);

    // layer 1
    qkv_kernel<<<128, 256, 0, stream>>>(xsrc, pe, q1_w, k1_w, v1_w, q, k, v);
    attn_kernel<<<dim3(BB * HH, 4), 256, 0, stream>>>(q, k, v, ao);
    post_kernel<<<128, 256, 0, stream>>>(ao, xsrc, lna1_g, lna1_b, ln1_g, ln1_b, z);

    // layer 2
    qkv_kernel<<<128, 256, 0, stream>>>(z, pe, q2_w, k2_w, v2_w, q, k, v);
    attn_kernel<<<dim3(BB * HH, 4), 256, 0, stream>>>(q, k, v, ao);
    post_kernel<<<128, 256, 0, stream>>>(ao, nullptr, lna2_g, lna2_b, ln2_g, ln2_b, z2);

    pool_kernel<<<BB, 256, 0, stream>>>(z2, out_w, out_b, out);
}

// Round 2
// 387.233 us; speedup vs baseline: 1.4012x; 1.4012x over previous
//
#include <hip/hip_runtime.h>
#include <hip/hip_bf16.h>
#include <math.h>

// Problem constants
#define BB 32
#define LL 4100
#define SS 1024
#define EE 16
#define HH 4
#define DHD 4
#define NCC 10
#define TSPLIT 2
#define TCHUNK (SS / TSPLIT)   // 512

// Workspace layout (in floats)
#define OFF_PE   0                       // S*E = 16384
#define OFF_H1   16384                   // B*8*S = 262144 (convs; reused as attn partials)
#define OFF_H2   (OFF_H1 + 262144)       // B*32*S = 1048576
#define OFF_XSRC (OFF_H2 + 1048576)      // B*S*E = 524288
#define OFF_Q    (OFF_XSRC + 524288)     // B*H*S*DH = 524288
#define OFF_K    (OFF_Q + 524288)
#define OFF_V    (OFF_K + 524288)
#define OFF_Z    (OFF_V + 524288)        // layer-1 output
#define OFF_Z2   OFF_XSRC                // reuse xsrc for final z2 (xsrc dead after post1)
// attn partials overwrite H1+H2 region (dead after conv3):
//   partO: TSPLIT*B*H*S float4 = 2*128*1024*4 = 1,048,576 floats
//   partL: TSPLIT*B*H*S        =               262,144 floats
#define OFF_PARTO OFF_H1
#define OFF_PARTL (OFF_PARTO + 1048576)

__global__ __launch_bounds__(256) void pe_kernel(float* pe) {
    int idx = blockIdx.x * 256 + threadIdx.x;       // S*E = 16384
    int s = idx >> 4, e = idx & 15;
    int j = e >> 1;
    // 10000^(-j/8) = exp2(j * -log2(10000)/8)
    float div = exp2f((float)j * -1.66096404744f);
    float ang = (float)s * div * (16.f / 1024.f);
    pe[idx] = (e & 1) ? cosf(ang) : sinf(ang);
}

__global__ __launch_bounds__(256) void conv1_kernel(const float* __restrict__ x,
        const float* __restrict__ w, const float* __restrict__ bias,
        const float* __restrict__ g, const float* __restrict__ bb,
        float* __restrict__ h1) {
    int idx = blockIdx.x * 256 + threadIdx.x;       // B*8*S
    int s = idx & 1023; int c = (idx >> 10) & 7; int b = idx >> 13;
    const float* xp = x + b * LL + 4 * s;
    float acc = bias[c];
    #pragma unroll
    for (int k = 0; k < 8; k++) acc += xp[k] * w[c * 8 + k];
    float inv = rsqrtf(1.f + 1e-5f);
    float v = acc * inv * g[c] + bb[c];
    h1[idx] = fmaxf(v, 0.f);
}

__global__ __launch_bounds__(256) void conv2_kernel(const float* __restrict__ h1,
        const float* __restrict__ w, const float* __restrict__ bias,
        const float* __restrict__ g, const float* __restrict__ bb,
        float* __restrict__ h2) {
    int s = blockIdx.x * 256 + threadIdx.x;
    int o = blockIdx.y, b = blockIdx.z;
    const float* hp = h1 + b * 8 * SS;
    float acc = bias[o];
    #pragma unroll
    for (int i = 0; i < 8; i++) {
        const float* row = hp + i * SS;
        const float* wr = w + (o * 8 + i) * 8;
        #pragma unroll
        for (int k = 0; k < 8; k++) {
            int t = s - 3 + k;
            if (t >= 0 && t < SS) acc += row[t] * wr[k];
        }
    }
    float inv = rsqrtf(1.f + 1e-5f);
    float v = acc * inv * g[o] + bb[o];
    h2[(b * 32 + o) * SS + s] = fmaxf(v, 0.f);
}

__global__ __launch_bounds__(256) void conv3_kernel(const float* __restrict__ h2,
        const float* __restrict__ dw, const float* __restrict__ pw,
        const float* __restrict__ g, const float* __restrict__ bb,
        float* __restrict__ xsrc) {
    __shared__ float sdw[1024], spw[256];
    int tid = threadIdx.x;
    for (int i = tid; i < 1024; i += 256) sdw[i] = dw[i];
    spw[tid] = pw[tid];
    __syncthreads();
    int s = blockIdx.x * 256 + tid; int b = blockIdx.y;
    const float* hb = h2 + b * 32 * SS;
    float gout[16];
    #pragma unroll 4
    for (int o = 0; o < 16; o++) {
        float acc = 0.f;
        #pragma unroll
        for (int c = 0; c < 2; c++) {
            const float* row = hb + (2 * o + c) * SS;
            const float* wr = sdw + (o * 2 + c) * 32;
            #pragma unroll
            for (int k = 0; k < 32; k++) {
                int t = s - 15 + k;
                if (t >= 0 && t < SS) acc += row[t] * wr[k];
            }
        }
        gout[o] = acc;
    }
    float inv = rsqrtf(1.f + 1e-5f);
    float* xp = xsrc + (b * SS + s) * 16;
    #pragma unroll
    for (int p = 0; p < 16; p++) {
        float acc = 0.f;
        #pragma unroll
        for (int o = 0; o < 16; o++) acc += spw[p * 16 + o] * gout[o];
        float v = acc * inv * g[p] + bb[p];
        xp[p] = fmaxf(v, 0.f);
    }
}

// QKV projection: t = xin[b,s,:] + pe[s,:];  {q,k,v}[e] = sum_f W[e,f]*t[f]
// Output layout: [B,H,S,DH] for contiguous float4 reads in attention.
__global__ __launch_bounds__(256) void qkv_kernel(const float* __restrict__ xin,
        const float* __restrict__ pe,
        const float* __restrict__ wq, const float* __restrict__ wk,
        const float* __restrict__ wv,
        float* __restrict__ q, float* __restrict__ k, float* __restrict__ v) {
    __shared__ float swq[256], swk[256], swv[256];
    int tid = threadIdx.x;
    swq[tid] = wq[tid]; swk[tid] = wk[tid]; swv[tid] = wv[tid];
    __syncthreads();
    int idx = blockIdx.x * 256 + tid;               // b*S + s
    int s = idx & 1023; int b = idx >> 10;
    float t[16];
    const float4* xp4 = (const float4*)(xin + (size_t)idx * 16);
    const float4* pp4 = (const float4*)(pe + s * 16);
    #pragma unroll
    for (int i = 0; i < 4; i++) {
        float4 a = xp4[i], p = pp4[i];
        t[4*i+0] = a.x + p.x; t[4*i+1] = a.y + p.y;
        t[4*i+2] = a.z + p.z; t[4*i+3] = a.w + p.w;
    }
    #pragma unroll
    for (int e = 0; e < 16; e++) {
        float aq = 0.f, ak = 0.f, av = 0.f;
        #pragma unroll
        for (int f = 0; f < 16; f++) {
            aq += swq[e * 16 + f] * t[f];
            ak += swk[e * 16 + f] * t[f];
            av += swv[e * 16 + f] * t[f];
        }
        int h = e >> 2, d = e & 3;
        size_t o = ((size_t)(b * HH + h) * SS + s) * DHD + d;
        q[o] = aq; k[o] = ak; v[o] = av;
    }
}

// Attention core, single-pass no-max softmax with t-split.
// Scores sc = (q.k) * scale * |t-s|/n are O(1) — exp without max subtraction is
// exact math and fp32-safe. Partial sums over t-chunks are exactly associative.
// Block: (bh, s-chunk of 256, t-chunk). K,V chunk LDS-resident (16 KB).
__global__ __launch_bounds__(256) void attn_kernel(const float* __restrict__ q,
        const float* __restrict__ k, const float* __restrict__ v,
        float* __restrict__ partO, float* __restrict__ partL) {
    __shared__ float4 Ks[TCHUNK], Vs[TCHUNK];
    int bh = blockIdx.x;                             // b*H + h
    int tid = threadIdx.x;
    int tc = blockIdx.z;
    int t0 = tc * TCHUNK;
    const float4* kp = (const float4*)(k + (size_t)bh * SS * DHD) + t0;
    const float4* vp = (const float4*)(v + (size_t)bh * SS * DHD) + t0;
    for (int t = tid; t < TCHUNK; t += 256) { Ks[t] = kp[t]; Vs[t] = vp[t]; }
    __syncthreads();
    int s = blockIdx.y * 256 + tid;
    float4 qv = ((const float4*)(q + (size_t)bh * SS * DHD))[s];
    // fold scale * 1/n * log2(e) into q so inner loop is: p = exp2((q.k) * |t-s|)
    const float cs = (0.25f / 1024.f) * 1.44269504089f;
    qv.x *= cs; qv.y *= cs; qv.z *= cs; qv.w *= cs;
    float tf = (float)(t0 - s);
    float l = 0.f, ox = 0.f, oy = 0.f, oz = 0.f, ow = 0.f;
    #pragma unroll 4
    for (int t = 0; t < TCHUNK; t++) {
        float4 kk = Ks[t];
        float d = qv.x*kk.x + qv.y*kk.y + qv.z*kk.z + qv.w*kk.w;
        float p = exp2f(d * fabsf(tf));
        tf += 1.f;
        float4 vv = Vs[t];
        l += p; ox += p*vv.x; oy += p*vv.y; oz += p*vv.z; ow += p*vv.w;
    }
    size_t o = (size_t)(tc * (BB * HH) + bh) * SS + s;
    ((float4*)partO)[o] = make_float4(ox, oy, oz, ow);
    partL[o] = l;
}

// Fused epilogue: combine attn partials, y = LN(., lna); z = LN(y + res, ln)
__global__ __launch_bounds__(256) void post_kernel(const float* __restrict__ partO,
        const float* __restrict__ partL,
        const float* __restrict__ res,
        const float* __restrict__ lna_g, const float* __restrict__ lna_b,
        const float* __restrict__ ln_g, const float* __restrict__ ln_b,
        float* __restrict__ z) {
    int idx = blockIdx.x * 256 + threadIdx.x;        // b*S+s
    int b = idx >> 10, s = idx & 1023;
    float t[16];
    #pragma unroll
    for (int h = 0; h < HH; h++) {
        int bh = b * HH + h;
        size_t o0 = (size_t)bh * SS + s;
        size_t o1 = (size_t)(BB * HH + bh) * SS + s;
        float4 O0 = ((const float4*)partO)[o0];
        float4 O1 = ((const float4*)partO)[o1];
        float rl = 1.f / (partL[o0] + partL[o1]);
        t[h*4+0] = (O0.x + O1.x) * rl;
        t[h*4+1] = (O0.y + O1.y) * rl;
        t[h*4+2] = (O0.z + O1.z) * rl;
        t[h*4+3] = (O0.w + O1.w) * rl;
    }
    float mu = 0.f;
    #pragma unroll
    for (int e = 0; e < 16; e++) mu += t[e];
    mu *= (1.f / 16.f);
    float var = 0.f;
    #pragma unroll
    for (int e = 0; e < 16; e++) { float d = t[e] - mu; var += d * d; }
    var *= (1.f / 16.f);
    float r = rsqrtf(var + 1e-5f);
    if (res) {
        const float4* rp = (const float4*)(res + (size_t)idx * 16);
        #pragma unroll
        for (int i = 0; i < 4; i++) {
            float4 a = rp[i];
            t[4*i+0] = (t[4*i+0]-mu)*r*lna_g[4*i+0] + lna_b[4*i+0] + a.x;
            t[4*i+1] = (t[4*i+1]-mu)*r*lna_g[4*i+1] + lna_b[4*i+1] + a.y;
            t[4*i+2] = (t[4*i+2]-mu)*r*lna_g[4*i+2] + lna_b[4*i+2] + a.z;
            t[4*i+3] = (t[4*i+3]-mu)*r*lna_g[4*i+3] + lna_b[4*i+3] + a.w;
        }
    } else {
        #pragma unroll
        for (int e = 0; e < 16; e++) t[e] = (t[e]-mu)*r*lna_g[e] + lna_b[e];
    }
    float mu2 = 0.f;
    #pragma unroll
    for (int e = 0; e < 16; e++) mu2 += t[e];
    mu2 *= (1.f / 16.f);
    float var2 = 0.f;
    #pragma unroll
    for (int e = 0; e < 16; e++) { float d = t[e] - mu2; var2 += d * d; }
    var2 *= (1.f / 16.f);
    float r2 = rsqrtf(var2 + 1e-5f);
    float4* zp = (float4*)(z + (size_t)idx * 16);
    #pragma unroll
    for (int i = 0; i < 4; i++) {
        float4 o;
        o.x = (t[4*i+0]-mu2)*r2*ln_g[4*i+0] + ln_b[4*i+0];
        o.y = (t[4*i+1]-mu2)*r2*ln_g[4*i+1] + ln_b[4*i+1];
        o.z = (t[4*i+2]-mu2)*r2*ln_g[4*i+2] + ln_b[4*i+2];
        o.w = (t[4*i+3]-mu2)*r2*ln_g[4*i+3] + ln_b[4*i+3];
        zp[i] = o;
    }
}

// Global-average-pool over S + final linear [16 -> 10]
__global__ __launch_bounds__(256) void pool_kernel(const float* __restrict__ z2,
        const float* __restrict__ ow, const float* __restrict__ ob,
        float* __restrict__ out) {
    __shared__ float red[256 * 16];
    int b = blockIdx.x, tid = threadIdx.x;
    float acc[16];
    #pragma unroll
    for (int e = 0; e < 16; e++) acc[e] = 0.f;
    for (int s = tid; s < SS; s += 256) {
        const float4* zp = (const float4*)(z2 + ((size_t)(b * SS + s)) * 16);
        #pragma unroll
        for (int i = 0; i < 4; i++) {
            float4 a = zp[i];
            acc[4*i+0] += a.x; acc[4*i+1] += a.y;
            acc[4*i+2] += a.z; acc[4*i+3] += a.w;
        }
    }
    #pragma unroll
    for (int e = 0; e < 16; e++) red[tid * 16 + e] = acc[e];
    __syncthreads();
    for (int off = 128; off > 0; off >>= 1) {
        if (tid < off) {
            #pragma unroll
            for (int e = 0; e < 16; e++) red[tid * 16 + e] += red[(tid + off) * 16 + e];
        }
        __syncthreads();
    }
    if (tid < NCC) {
        float a = ob[tid];
        #pragma unroll
        for (int e = 0; e < 16; e++) a += (red[e] * (1.f / 1024.f)) * ow[tid * 16 + e];
        out[b * NCC + tid] = a;
    }
}

extern "C" void kernel_launch(void* const* d_in, const int* in_sizes, int n_in,
                              void* d_out, int out_size, void* d_ws, size_t ws_size,
                              hipStream_t stream) {
    const float* x       = (const float*)d_in[0];
    const float* patch_w = (const float*)d_in[1];
    const float* patch_b = (const float*)d_in[2];
    const float* bn1_g   = (const float*)d_in[3];
    const float* bn1_b   = (const float*)d_in[4];
    const float* emb_w   = (const float*)d_in[5];
    const float* emb_b   = (const float*)d_in[6];
    const float* bn2_g   = (const float*)d_in[7];
    const float* bn2_b   = (const float*)d_in[8];
    const float* dw_w    = (const float*)d_in[9];
    const float* pw_w    = (const float*)d_in[10];
    const float* bn3_g   = (const float*)d_in[11];
    const float* bn3_b   = (const float*)d_in[12];
    const float* q1_w    = (const float*)d_in[13];
    const float* k1_w    = (const float*)d_in[14];
    const float* v1_w    = (const float*)d_in[15];
    const float* lna1_g  = (const float*)d_in[16];
    const float* lna1_b  = (const float*)d_in[17];
    const float* ln1_g   = (const float*)d_in[18];
    const float* ln1_b   = (const float*)d_in[19];
    const float* q2_w    = (const float*)d_in[20];
    const float* k2_w    = (const float*)d_in[21];
    const float* v2_w    = (const float*)d_in[22];
    const float* lna2_g  = (const float*)d_in[23];
    const float* lna2_b  = (const float*)d_in[24];
    const float* ln2_g   = (const float*)d_in[25];
    const float* ln2_b   = (const float*)d_in[26];
    const float* out_w   = (const float*)d_in[27];
    const float* out_b   = (const float*)d_in[28];

    float* ws    = (float*)d_ws;
    float* pe    = ws + OFF_PE;
    float* h1    = ws + OFF_H1;
    float* h2    = ws + OFF_H2;
    float* xsrc  = ws + OFF_XSRC;
    float* q     = ws + OFF_Q;
    float* k     = ws + OFF_K;
    float* v     = ws + OFF_V;
    float* z     = ws + OFF_Z;
    float* z2    = ws + OFF_Z2;
    float* partO = ws + OFF_PARTO;
    float* partL = ws + OFF_PARTL;
    float* out   = (float*)d_out;

    pe_kernel<<<64, 256, 0, stream>>>(pe);
    conv1_kernel<<<1024, 256, 0, stream>>>(x, patch_w, patch_b, bn1_g, bn1_b, h1);
    conv2_kernel<<<dim3(4, 32, BB), 256, 0, stream>>>(h1, emb_w, emb_b, bn2_g, bn2_b, h2);
    conv3_kernel<<<dim3(4, BB), 256, 0, stream>>>(h2, dw_w, pw_w, bn3_g, bn3_b, xsrc);

    // layer 1
    qkv_kernel<<<128, 256, 0, stream>>>(xsrc, pe, q1_w, k1_w, v1_w, q, k, v);
    attn_kernel<<<dim3(BB * HH, 4, TSPLIT), 256, 0, stream>>>(q, k, v, partO, partL);
    post_kernel<<<128, 256, 0, stream>>>(partO, partL, xsrc, lna1_g, lna1_b, ln1_g, ln1_b, z);

    // layer 2
    qkv_kernel<<<128, 256, 0, stream>>>(z, pe, q2_w, k2_w, v2_w, q, k, v);
    attn_kernel<<<dim3(BB * HH, 4, TSPLIT), 256, 0, stream>>>(q, k, v, partO, partL);
    post_kernel<<<128, 256, 0, stream>>>(partO, partL, nullptr, lna2_g, lna2_b, ln2_g, ln2_b, z2);

    pool_kernel<<<BB, 256, 0, stream>>>(z2, out_w, out_b, out);
}

// Round 3
// 310.528 us; speedup vs baseline: 1.7473x; 1.2470x over previous
//
#include <hip/hip_runtime.h>
#include <hip/hip_bf16.h>
#include <math.h>

// Problem constants
#define BB 32
#define LL 4100
#define SS 1024
#define EE 16
#define HH 4
#define DHD 4
#define NCC 10

// Workspace layout (in floats)
#define OFF_PE   0                       // S*E = 16384
#define OFF_H1   16384                   // B*8*S = 262144
#define OFF_H2   (OFF_H1 + 262144)       // B*32*S = 1048576
#define OFF_XSRC (OFF_H2 + 1048576)      // B*S*E = 524288
#define OFF_Q    (OFF_XSRC + 524288)     // B*H*S*DH = 524288 (also gdw temp before qkv)
#define OFF_K    (OFF_Q + 524288)
#define OFF_V    (OFF_K + 524288)
#define OFF_Z    (OFF_V + 524288)        // layer-1 output
#define OFF_END  (OFF_Z + 524288)        // 3,948,544 floats = 15.8 MB
#define OFF_Z2   OFF_XSRC                // reuse xsrc for final z2 (xsrc dead after post1)
// attn partials, fallback region (TSPLIT=2): overlays H1+H2 (dead after conv3)
//   partO: 2*B*H*S float4 = 1,048,576 floats ; partL: 262,144 floats

__global__ __launch_bounds__(256) void pe_kernel(float* pe) {
    int idx = blockIdx.x * 256 + threadIdx.x;       // S*E = 16384
    int s = idx >> 4, e = idx & 15;
    int j = e >> 1;
    float div = exp2f((float)j * -1.66096404744f);  // 10000^(-j/8)
    float ang = (float)s * div * (16.f / 1024.f);
    pe[idx] = (e & 1) ? cosf(ang) : sinf(ang);
}

__global__ __launch_bounds__(256) void conv1_kernel(const float* __restrict__ x,
        const float* __restrict__ w, const float* __restrict__ bias,
        const float* __restrict__ g, const float* __restrict__ bb,
        float* __restrict__ h1) {
    int idx = blockIdx.x * 256 + threadIdx.x;       // B*8*S
    int s = idx & 1023; int c = (idx >> 10) & 7; int b = idx >> 13;
    const float* xp = x + b * LL + 4 * s;
    float acc = bias[c];
    #pragma unroll
    for (int k = 0; k < 8; k++) acc += xp[k] * w[c * 8 + k];
    float inv = rsqrtf(1.f + 1e-5f);
    float v = acc * inv * g[c] + bb[c];
    h1[idx] = fmaxf(v, 0.f);
}

__global__ __launch_bounds__(256) void conv2_kernel(const float* __restrict__ h1,
        const float* __restrict__ w, const float* __restrict__ bias,
        const float* __restrict__ g, const float* __restrict__ bb,
        float* __restrict__ h2) {
    int s = blockIdx.x * 256 + threadIdx.x;
    int o = blockIdx.y, b = blockIdx.z;
    const float* hp = h1 + b * 8 * SS;
    float acc = bias[o];
    #pragma unroll
    for (int i = 0; i < 8; i++) {
        const float* row = hp + i * SS;
        const float* wr = w + (o * 8 + i) * 8;
        #pragma unroll
        for (int k = 0; k < 8; k++) {
            int t = s - 3 + k;
            if (t >= 0 && t < SS) acc += row[t] * wr[k];
        }
    }
    float inv = rsqrtf(1.f + 1e-5f);
    float v = acc * inv * g[o] + bb[o];
    h2[(b * 32 + o) * SS + s] = fmaxf(v, 0.f);
}

// Depthwise grouped conv (32->16, k=32, groups=16): thread = (b, o, s).
// 2048 blocks -> 8 blocks/CU; loads are coalesced and heavily L1-reused.
__global__ __launch_bounds__(256) void dw_kernel(const float* __restrict__ h2,
        const float* __restrict__ dw, float* __restrict__ gdw) {
    int s = blockIdx.x * 256 + threadIdx.x;
    int o = blockIdx.y, b = blockIdx.z;
    const float* r0 = h2 + (size_t)(b * 32 + 2 * o) * SS;
    const float* r1 = r0 + SS;
    const float* w0 = dw + (o * 2) * 32;   // uniform -> scalar loads
    const float* w1 = w0 + 32;
    float acc = 0.f;
    #pragma unroll
    for (int kk = 0; kk < 32; kk++) {
        int t = s - 15 + kk;
        if (t >= 0 && t < SS) acc += r0[t] * w0[kk] + r1[t] * w1[kk];
    }
    gdw[(size_t)(b * 16 + o) * SS + s] = acc;
}

// Pointwise 1x1 conv (16->16) + BN + ReLU, output pre-transposed [B,S,16]
__global__ __launch_bounds__(256) void pw_kernel(const float* __restrict__ gdw,
        const float* __restrict__ pw, const float* __restrict__ g,
        const float* __restrict__ bb, float* __restrict__ xsrc) {
    __shared__ float spw[256];
    int tid = threadIdx.x;
    spw[tid] = pw[tid];
    __syncthreads();
    int idx = blockIdx.x * 256 + tid;               // b*S + s
    int s = idx & 1023, b = idx >> 10;
    float gout[16];
    #pragma unroll
    for (int o = 0; o < 16; o++) gout[o] = gdw[(size_t)(b * 16 + o) * SS + s];
    float inv = rsqrtf(1.f + 1e-5f);
    float* xp = xsrc + (size_t)idx * 16;
    #pragma unroll
    for (int p = 0; p < 16; p++) {
        float acc = 0.f;
        #pragma unroll
        for (int o = 0; o < 16; o++) acc += spw[p * 16 + o] * gout[o];
        float v = acc * inv * g[p] + bb[p];
        xp[p] = fmaxf(v, 0.f);
    }
}

// QKV projection: t = xin[b,s,:] + pe[s,:];  {q,k,v}[e] = sum_f W[e,f]*t[f]
// Output layout: [B,H,S,DH] for contiguous float4 reads in attention.
__global__ __launch_bounds__(256) void qkv_kernel(const float* __restrict__ xin,
        const float* __restrict__ pe,
        const float* __restrict__ wq, const float* __restrict__ wk,
        const float* __restrict__ wv,
        float* __restrict__ q, float* __restrict__ k, float* __restrict__ v) {
    __shared__ float swq[256], swk[256], swv[256];
    int tid = threadIdx.x;
    swq[tid] = wq[tid]; swk[tid] = wk[tid]; swv[tid] = wv[tid];
    __syncthreads();
    int idx = blockIdx.x * 256 + tid;               // b*S + s
    int s = idx & 1023; int b = idx >> 10;
    float t[16];
    const float4* xp4 = (const float4*)(xin + (size_t)idx * 16);
    const float4* pp4 = (const float4*)(pe + s * 16);
    #pragma unroll
    for (int i = 0; i < 4; i++) {
        float4 a = xp4[i], p = pp4[i];
        t[4*i+0] = a.x + p.x; t[4*i+1] = a.y + p.y;
        t[4*i+2] = a.z + p.z; t[4*i+3] = a.w + p.w;
    }
    #pragma unroll
    for (int e = 0; e < 16; e++) {
        float aq = 0.f, ak = 0.f, av = 0.f;
        #pragma unroll
        for (int f = 0; f < 16; f++) {
            aq += swq[e * 16 + f] * t[f];
            ak += swk[e * 16 + f] * t[f];
            av += swv[e * 16 + f] * t[f];
        }
        int h = e >> 2, d = e & 3;
        size_t o = ((size_t)(b * HH + h) * SS + s) * DHD + d;
        q[o] = aq; k[o] = ak; v[o] = av;
    }
}

// Attention core, single-pass no-max softmax with t-split (runtime split count).
// Scores sc = (q.k)*scale*|t-s|/n are O(1) -> exp without max is exact and safe.
__global__ __launch_bounds__(256) void attn_kernel(const float* __restrict__ q,
        const float* __restrict__ k, const float* __restrict__ v,
        float* __restrict__ partO, float* __restrict__ partL) {
    __shared__ float4 Ks[512], Vs[512];
    int bh = blockIdx.x;                             // b*H + h
    int tid = threadIdx.x;
    int tsplit = gridDim.z;
    int tchunk = SS / tsplit;
    int tc = blockIdx.z;
    int t0 = tc * tchunk;
    const float4* kp = (const float4*)(k + (size_t)bh * SS * DHD) + t0;
    const float4* vp = (const float4*)(v + (size_t)bh * SS * DHD) + t0;
    for (int t = tid; t < tchunk; t += 256) { Ks[t] = kp[t]; Vs[t] = vp[t]; }
    __syncthreads();
    int s = blockIdx.y * 256 + tid;
    float4 qv = ((const float4*)(q + (size_t)bh * SS * DHD))[s];
    // fold scale * 1/n * log2(e) into q so inner loop is: p = exp2((q.k) * |t-s|)
    const float cs = (0.25f / 1024.f) * 1.44269504089f;
    qv.x *= cs; qv.y *= cs; qv.z *= cs; qv.w *= cs;
    float tf = (float)(t0 - s);
    float l = 0.f, ox = 0.f, oy = 0.f, oz = 0.f, ow = 0.f;
    #pragma unroll 4
    for (int t = 0; t < tchunk; t++) {
        float4 kk = Ks[t];
        float d = qv.x*kk.x + qv.y*kk.y + qv.z*kk.z + qv.w*kk.w;
        float p = exp2f(d * fabsf(tf));
        tf += 1.f;
        float4 vv = Vs[t];
        l += p; ox += p*vv.x; oy += p*vv.y; oz += p*vv.z; ow += p*vv.w;
    }
    size_t o = (size_t)(tc * (BB * HH) + bh) * SS + s;
    ((float4*)partO)[o] = make_float4(ox, oy, oz, ow);
    partL[o] = l;
}

// Fused epilogue: combine attn partials, y = LN(., lna); z = LN(y + res, ln)
__global__ __launch_bounds__(256) void post_kernel(const float* __restrict__ partO,
        const float* __restrict__ partL, int nsplit,
        const float* __restrict__ res,
        const float* __restrict__ lna_g, const float* __restrict__ lna_b,
        const float* __restrict__ ln_g, const float* __restrict__ ln_b,
        float* __restrict__ z) {
    int idx = blockIdx.x * 256 + threadIdx.x;        // b*S+s
    int b = idx >> 10, s = idx & 1023;
    float t[16];
    #pragma unroll
    for (int h = 0; h < HH; h++) {
        int bh = b * HH + h;
        float ox = 0.f, oy = 0.f, oz = 0.f, ow = 0.f, l = 0.f;
        for (int c = 0; c < nsplit; c++) {
            size_t o = (size_t)(c * (BB * HH) + bh) * SS + s;
            float4 O = ((const float4*)partO)[o];
            ox += O.x; oy += O.y; oz += O.z; ow += O.w;
            l += partL[o];
        }
        float rl = 1.f / l;
        t[h*4+0] = ox * rl; t[h*4+1] = oy * rl;
        t[h*4+2] = oz * rl; t[h*4+3] = ow * rl;
    }
    float mu = 0.f;
    #pragma unroll
    for (int e = 0; e < 16; e++) mu += t[e];
    mu *= (1.f / 16.f);
    float var = 0.f;
    #pragma unroll
    for (int e = 0; e < 16; e++) { float d = t[e] - mu; var += d * d; }
    var *= (1.f / 16.f);
    float r = rsqrtf(var + 1e-5f);
    if (res) {
        const float4* rp = (const float4*)(res + (size_t)idx * 16);
        #pragma unroll
        for (int i = 0; i < 4; i++) {
            float4 a = rp[i];
            t[4*i+0] = (t[4*i+0]-mu)*r*lna_g[4*i+0] + lna_b[4*i+0] + a.x;
            t[4*i+1] = (t[4*i+1]-mu)*r*lna_g[4*i+1] + lna_b[4*i+1] + a.y;
            t[4*i+2] = (t[4*i+2]-mu)*r*lna_g[4*i+2] + lna_b[4*i+2] + a.z;
            t[4*i+3] = (t[4*i+3]-mu)*r*lna_g[4*i+3] + lna_b[4*i+3] + a.w;
        }
    } else {
        #pragma unroll
        for (int e = 0; e < 16; e++) t[e] = (t[e]-mu)*r*lna_g[e] + lna_b[e];
    }
    float mu2 = 0.f;
    #pragma unroll
    for (int e = 0; e < 16; e++) mu2 += t[e];
    mu2 *= (1.f / 16.f);
    float var2 = 0.f;
    #pragma unroll
    for (int e = 0; e < 16; e++) { float d = t[e] - mu2; var2 += d * d; }
    var2 *= (1.f / 16.f);
    float r2 = rsqrtf(var2 + 1e-5f);
    float4* zp = (float4*)(z + (size_t)idx * 16);
    #pragma unroll
    for (int i = 0; i < 4; i++) {
        float4 o;
        o.x = (t[4*i+0]-mu2)*r2*ln_g[4*i+0] + ln_b[4*i+0];
        o.y = (t[4*i+1]-mu2)*r2*ln_g[4*i+1] + ln_b[4*i+1];
        o.z = (t[4*i+2]-mu2)*r2*ln_g[4*i+2] + ln_b[4*i+2];
        o.w = (t[4*i+3]-mu2)*r2*ln_g[4*i+3] + ln_b[4*i+3];
        zp[i] = o;
    }
}

// Global-average-pool over S + final linear [16 -> 10]
__global__ __launch_bounds__(256) void pool_kernel(const float* __restrict__ z2,
        const float* __restrict__ ow, const float* __restrict__ ob,
        float* __restrict__ out) {
    __shared__ float red[256 * 16];
    int b = blockIdx.x, tid = threadIdx.x;
    float acc[16];
    #pragma unroll
    for (int e = 0; e < 16; e++) acc[e] = 0.f;
    for (int s = tid; s < SS; s += 256) {
        const float4* zp = (const float4*)(z2 + ((size_t)(b * SS + s)) * 16);
        #pragma unroll
        for (int i = 0; i < 4; i++) {
            float4 a = zp[i];
            acc[4*i+0] += a.x; acc[4*i+1] += a.y;
            acc[4*i+2] += a.z; acc[4*i+3] += a.w;
        }
    }
    #pragma unroll
    for (int e = 0; e < 16; e++) red[tid * 16 + e] = acc[e];
    __syncthreads();
    for (int off = 128; off > 0; off >>= 1) {
        if (tid < off) {
            #pragma unroll
            for (int e = 0; e < 16; e++) red[tid * 16 + e] += red[(tid + off) * 16 + e];
        }
        __syncthreads();
    }
    if (tid < NCC) {
        float a = ob[tid];
        #pragma unroll
        for (int e = 0; e < 16; e++) a += (red[e] * (1.f / 1024.f)) * ow[tid * 16 + e];
        out[b * NCC + tid] = a;
    }
}

extern "C" void kernel_launch(void* const* d_in, const int* in_sizes, int n_in,
                              void* d_out, int out_size, void* d_ws, size_t ws_size,
                              hipStream_t stream) {
    const float* x       = (const float*)d_in[0];
    const float* patch_w = (const float*)d_in[1];
    const float* patch_b = (const float*)d_in[2];
    const float* bn1_g   = (const float*)d_in[3];
    const float* bn1_b   = (const float*)d_in[4];
    const float* emb_w   = (const float*)d_in[5];
    const float* emb_b   = (const float*)d_in[6];
    const float* bn2_g   = (const float*)d_in[7];
    const float* bn2_b   = (const float*)d_in[8];
    const float* dw_w    = (const float*)d_in[9];
    const float* pw_w    = (const float*)d_in[10];
    const float* bn3_g   = (const float*)d_in[11];
    const float* bn3_b   = (const float*)d_in[12];
    const float* q1_w    = (const float*)d_in[13];
    const float* k1_w    = (const float*)d_in[14];
    const float* v1_w    = (const float*)d_in[15];
    const float* lna1_g  = (const float*)d_in[16];
    const float* lna1_b  = (const float*)d_in[17];
    const float* ln1_g   = (const float*)d_in[18];
    const float* ln1_b   = (const float*)d_in[19];
    const float* q2_w    = (const float*)d_in[20];
    const float* k2_w    = (const float*)d_in[21];
    const float* v2_w    = (const float*)d_in[22];
    const float* lna2_g  = (const float*)d_in[23];
    const float* lna2_b  = (const float*)d_in[24];
    const float* ln2_g   = (const float*)d_in[25];
    const float* ln2_b   = (const float*)d_in[26];
    const float* out_w   = (const float*)d_in[27];
    const float* out_b   = (const float*)d_in[28];

    float* ws    = (float*)d_ws;
    float* pe    = ws + OFF_PE;
    float* h1    = ws + OFF_H1;
    float* h2    = ws + OFF_H2;
    float* xsrc  = ws + OFF_XSRC;
    float* gdw   = ws + OFF_Q;      // temp; dead once qkv writes q
    float* q     = ws + OFF_Q;
    float* k     = ws + OFF_K;
    float* v     = ws + OFF_V;
    float* z     = ws + OFF_Z;
    float* z2    = ws + OFF_Z2;
    float* out   = (float*)d_out;

    // attn split: 4-way if workspace allows (2048 blocks -> 8/CU), else 2-way
    int tsplit; float *partO, *partL;
    size_t need4 = (size_t)(OFF_END + 4 * 131072 * 4 + 4 * 131072) * 4;
    if (ws_size >= need4) {
        tsplit = 4;
        partO = ws + OFF_END;                       // 2,097,152 floats
        partL = ws + OFF_END + 2097152;             //   524,288 floats
    } else {
        tsplit = 2;
        partO = ws + OFF_H1;                        // overlays dead H1/H2
        partL = ws + OFF_H1 + 1048576;
    }

    pe_kernel<<<64, 256, 0, stream>>>(pe);
    conv1_kernel<<<1024, 256, 0, stream>>>(x, patch_w, patch_b, bn1_g, bn1_b, h1);
    conv2_kernel<<<dim3(4, 32, BB), 256, 0, stream>>>(h1, emb_w, emb_b, bn2_g, bn2_b, h2);
    dw_kernel<<<dim3(4, 16, BB), 256, 0, stream>>>(h2, dw_w, gdw);
    pw_kernel<<<128, 256, 0, stream>>>(gdw, pw_w, bn3_g, bn3_b, xsrc);

    // layer 1
    qkv_kernel<<<128, 256, 0, stream>>>(xsrc, pe, q1_w, k1_w, v1_w, q, k, v);
    attn_kernel<<<dim3(BB * HH, 4, tsplit), 256, 0, stream>>>(q, k, v, partO, partL);
    post_kernel<<<128, 256, 0, stream>>>(partO, partL, tsplit, xsrc, lna1_g, lna1_b, ln1_g, ln1_b, z);

    // layer 2
    qkv_kernel<<<128, 256, 0, stream>>>(z, pe, q2_w, k2_w, v2_w, q, k, v);
    attn_kernel<<<dim3(BB * HH, 4, tsplit), 256, 0, stream>>>(q, k, v, partO, partL);
    post_kernel<<<128, 256, 0, stream>>>(partO, partL, tsplit, nullptr, lna2_g, lna2_b, ln2_g, ln2_b, z2);

    pool_kernel<<<BB, 256, 0, stream>>>(z2, out_w, out_b, out);
}